// Round 9
// baseline (297.437 us; speedup 1.0000x reference)
//
#include <hip/hip_runtime.h>
#include <hip/hip_bf16.h>
#include <stdint.h>

using bf16 = __hip_bfloat16;

typedef __bf16 bf16x8 __attribute__((ext_vector_type(8)));
typedef float  f32x4  __attribute__((ext_vector_type(4)));

__device__ __forceinline__ float bflo(uint32_t u) { return __uint_as_float(u << 16); }
__device__ __forceinline__ float bfhi(uint32_t u) { return __uint_as_float(u & 0xffff0000u); }

__device__ __forceinline__ void load8(const bf16* p, float* f) {
  uint4 u = *(const uint4*)p;
  f[0] = bflo(u.x); f[1] = bfhi(u.x);
  f[2] = bflo(u.y); f[3] = bfhi(u.y);
  f[4] = bflo(u.z); f[5] = bfhi(u.z);
  f[6] = bflo(u.w); f[7] = bfhi(u.w);
}
__device__ __forceinline__ void load8(const float* p, float* f) {
  float4 a = *(const float4*)p, b = *(const float4*)(p + 4);
  f[0] = a.x; f[1] = a.y; f[2] = a.z; f[3] = a.w;
  f[4] = b.x; f[5] = b.y; f[6] = b.z; f[7] = b.w;
}
__device__ __forceinline__ void store1(float* o, float v) { *o = v; }
__device__ __forceinline__ void store1(bf16* o, float v) { *o = __float2bfloat16(v); }
__device__ __forceinline__ uint32_t bfbits(float x) {
  bf16 v = __float2bfloat16(x);
  return (uint32_t)*(uint16_t*)&v;
}

// ---- async global->LDS, 16B per lane; lds base must be wave-uniform -------
typedef const uint32_t __attribute__((address_space(1)))* gp_t;
typedef uint32_t __attribute__((address_space(3)))* lp_t;
__device__ __forceinline__ void gload16(const void* g, void* l) {
  __builtin_amdgcn_global_load_lds((gp_t)g, (lp_t)l, 16, 0, 0);
}

// ---------------------------------------------------------------------------
// Fused prologue (one launch, block-range dispatch):
//  blocks 0..511     : mask_pack  (needs 33 KB LDS)
//  blocks 512..3071  : cvt5 f32->bf16 of x,Wqkv,Wo,W1,W2
//  blocks 3072..3076 : prep_small (Wp/Wc rows + bias concat)
// ---------------------------------------------------------------------------
__global__ __launch_bounds__(256)
void prologue(const float* __restrict__ pm, const int* __restrict__ hid,
              const int* __restrict__ padm, uint32_t* __restrict__ mout,
              const float* __restrict__ x, const float* __restrict__ Wqkv,
              const float* __restrict__ Wo, const float* __restrict__ W1,
              const float* __restrict__ W2, bf16* __restrict__ xb,
              bf16* __restrict__ wq, bf16* __restrict__ wob,
              bf16* __restrict__ w1b, bf16* __restrict__ w2b,
              const float* __restrict__ bqkv, const float* __restrict__ bp,
              const float* __restrict__ bc, const float* __restrict__ Wp,
              const float* __restrict__ Wc, float* __restrict__ bias_ext)
{
  __shared__ float tileT[128][65];   // mask branch only
  const int blk = blockIdx.x, t = threadIdx.x;
  if (blk < 512) {
    // ---- mask_pack: out[b][q][k] = hid|pad ? FFFF.. : bf16(pmT)<<16|bf16(pm)
    const int k0 = (blk & 7) * 128, q0 = ((blk >> 3) & 15) * 64, b = blk >> 7;
    const size_t pb = (size_t)b << 20;
#pragma unroll
    for (int i = 0; i < 32; ++i) {   // stage pm[b][k0+r][q0+c]
      int idx = t + i * 256;
      int r = idx >> 6, c = idx & 63;
      tileT[r][c] = pm[pb + (size_t)(k0 + r) * 1024 + q0 + c];
    }
    __syncthreads();
#pragma unroll
    for (int i = 0; i < 32; ++i) {
      int idx = t + i * 256;         // 64 q x 128 k
      int q = idx >> 7, k = idx & 127;
      size_t src = pb + (size_t)(q0 + q) * 1024 + k0 + k;
      int msk = hid[src] | padm[b * 1024 + k0 + k];
      uint32_t u = 0xFFFFFFFFu;
      if (!msk) u = (bfbits(tileT[k][q]) << 16) | bfbits(pm[src]);
      mout[src] = u;
    }
  } else if (blk < 3072) {
    // ---- cvt5
    size_t j = ((size_t)(blk - 512) * 256 + t) * 8;
    const float* s; bf16* o; size_t off;
    if      (j < 2097152) { s = x;    o = xb;  off = j; }
    else if (j < 2883584) { s = Wqkv; o = wq;  off = j - 2097152; }
    else if (j < 3145728) { s = Wo;   o = wob; off = j - 2883584; }
    else if (j < 4194304) { s = W1;   o = w1b; off = j - 3145728; }
    else                  { s = W2;   o = w2b; off = j - 4194304; }
    float f[8];
    load8(s + off, f);
    uint4 u;
    u.x = (bfbits(f[1]) << 16) | bfbits(f[0]);
    u.y = (bfbits(f[3]) << 16) | bfbits(f[2]);
    u.z = (bfbits(f[5]) << 16) | bfbits(f[4]);
    u.w = (bfbits(f[7]) << 16) | bfbits(f[6]);
    *(uint4*)(o + off) = u;
  } else {
    // ---- prep_small
    int sb = blk - 3072;
    if (sb < 2) {
      int j = (sb * 256 + t) * 8;
      if (j < 4096) {
        float f[8]; load8(Wp + j, f);
#pragma unroll
        for (int i = 0; i < 8; ++i) wq[(size_t)1536 * 512 + j + i] = __float2bfloat16(f[i]);
      }
    } else if (sb < 4) {
      int j = ((sb - 2) * 256 + t) * 8;
      if (j < 4096) {
        float f[8]; load8(Wc + j, f);
#pragma unroll
        for (int i = 0; i < 8; ++i) wq[(size_t)1544 * 512 + j + i] = __float2bfloat16(f[i]);
      }
    } else {
      int j = t * 8;
#pragma unroll
      for (int i = 0; i < 8; ++i) {
        int cc = j + i;
        if (cc < 1664) {
          float v = 0.f;
          if (cc < 1536) v = bqkv[cc];
          else if (cc < 1544) v = bp[cc - 1536];
          else if (cc < 1552) v = bc[cc - 1544];
          bias_ext[cc] = v;
        }
      }
    }
  }
}

// ---------------------------------------------------------------------------
// GEMM: C[M,Nout] = A[M,K(kOff..kOff+kLen)] * W^T + bias   (bf16, f32 accum)
// 128 x BN tile, global_load_lds(16B) staging, 4 waves.
// MODE 0: bf16 store. MODE 1: relu+bf16. MODE 3: f32 split-K partial.
// MODE 2: QKV+pb/cb: cols 0-511 Q (x0.125) -> [0][b][h][n][d]; 512-1023 K;
//         1024-1535 V transposed [b][h][d][n]; 1536-1551 pb/cb f32; >=1552 skip
// ---------------------------------------------------------------------------
template<int MODE, int BN>
__global__ __launch_bounds__(256)
void gemm_bt(const bf16* __restrict__ A, const bf16* __restrict__ W,
             const float* __restrict__ bias, bf16* __restrict__ outb,
             float* __restrict__ outf, int M, int Nout, int K, int kLen)
{
  constexpr int NT = BN / 32;
  __shared__ bf16 As[128 * 64];
  __shared__ bf16 Bs[BN * 64];
  const int t = threadIdx.x, lane = t & 63, wave = t >> 6;
  const int m0 = blockIdx.y * 128, n0 = blockIdx.x * BN;
  const int kOff = blockIdx.z * kLen;
  if (MODE == 3) outf += (size_t)blockIdx.z * M * Nout;
  const int wr = wave >> 1, wc = wave & 1;
  const int frow = lane & 15, ksel = (lane >> 4) * 8;
  f32x4 acc[4 * NT] = {};
  const bf16* Ab = A + (size_t)m0 * K;
  const bf16* Wb = W + (size_t)n0 * K;

  for (int k0 = kOff; k0 < kOff + kLen; k0 += 64) {
    __syncthreads();
#pragma unroll
    for (int i = 0; i < 4; ++i) {
      int ib = i * 256 + wave * 64;
      int idx = ib + lane;
      gload16(Ab + (size_t)(idx >> 3) * K + k0 + (idx & 7) * 8, As + ib * 8);
    }
#pragma unroll
    for (int i = 0; i < BN / 32; ++i) {
      int ib = i * 256 + wave * 64;
      int idx = ib + lane;
      gload16(Wb + (size_t)(idx >> 3) * K + k0 + (idx & 7) * 8, Bs + ib * 8);
    }
    __syncthreads();
#pragma unroll
    for (int kk = 0; kk < 64; kk += 32) {
      bf16x8 af[4], bf_[NT];
#pragma unroll
      for (int mt = 0; mt < 4; ++mt)
        af[mt] = *(const bf16x8*)(As + (wr * 64 + mt * 16 + frow) * 64 + kk + ksel);
#pragma unroll
      for (int nt = 0; nt < NT; ++nt)
        bf_[nt] = *(const bf16x8*)(Bs + (wc * (BN / 2) + nt * 16 + frow) * 64 + kk + ksel);
#pragma unroll
      for (int mt = 0; mt < 4; ++mt)
#pragma unroll
        for (int nt = 0; nt < NT; ++nt)
          acc[mt * NT + nt] = __builtin_amdgcn_mfma_f32_16x16x32_bf16(
              af[mt], bf_[nt], acc[mt * NT + nt], 0, 0, 0);
    }
  }
  const int rb = (lane >> 4) * 4, cb = lane & 15;
#pragma unroll
  for (int mt = 0; mt < 4; ++mt)
#pragma unroll
    for (int nt = 0; nt < NT; ++nt) {
      f32x4 a = acc[mt * NT + nt];
#pragma unroll
      for (int r = 0; r < 4; ++r) {
        int row = m0 + wr * 64 + mt * 16 + rb + r;
        int col = n0 + wc * (BN / 2) + nt * 16 + cb;
        if (MODE == 3) {
          outf[(size_t)row * Nout + col] = a[r];
        } else {
          float v = a[r] + bias[col];
          if (MODE == 1) v = fmaxf(v, 0.f);
          if (MODE == 2) {
            if (col >= 1552) continue;           // padding cols
            int n = row >> 2, b = row & 3;
            if (col >= 1536) {                   // pb/cb projections, f32
              int j = col - 1536;
              int hh = j & 7;
              outf[(j < 8 ? 0 : 32768) + (b * 8 + hh) * 1024 + n] = v;
            } else {
              int which = col >> 9, hh = (col >> 6) & 7, d = col & 63;
              if (which == 0) v *= 0.125f;       // fold 1/sqrt(HD) into Q
              size_t idx;
              if (which == 2)   // V transposed: [b][h][d][n]
                idx = (((size_t)(64 + b * 8 + hh)) << 16) + (size_t)d * 1024 + n;
              else              // Q,K: [which][b][h][n][d]
                idx = (((size_t)(which * 32 + b * 8 + hh)) << 16) + (size_t)n * 64 + d;
              outb[idx] = __float2bfloat16(v);
            }
          } else {
            outb[(size_t)row * Nout + col] = __float2bfloat16(v);
          }
        }
      }
    }
}

// ---------------------------------------------------------------------------
// MFMA flash attention, S^T form. Block = 64 q of one (b,h); 4 waves x 16 q.
// K-tile = 64 keys (small LDS -> 6 blocks/CU for latency hiding).
// K/V staged via global_load_lds with XOR chunk swizzle on the GLOBAL side:
//   K[r][chunk] at LDS slot (r, chunk ^ (r&7));  V[d][chunk] at (d, chunk^(d&7))
// Lane owns one q-row; per-lane softmax; mask prefetch overlaps DMA.
// ---------------------------------------------------------------------------
__global__ __launch_bounds__(256, 6)
void attn_mfma(const bf16* __restrict__ qkv, const float* __restrict__ pbw,
               const float* __restrict__ cbw, const uint32_t* __restrict__ mpk,
               bf16* __restrict__ ctxo)
{
  __shared__ bf16 Kt[64 * 64];     // [key][d] swizzled (DMA)
  __shared__ bf16 Vt[64 * 64];     // [d][key] swizzled (DMA)
  __shared__ bf16 Ps[4][16][72];   // per-wave P [q][key], stride 72 -> 2-way
  const int t = threadIdx.x, lane = t & 63, wave = t >> 6;
  const int g = lane >> 4, c = lane & 15;
  const int h = blockIdx.y, b = blockIdx.z;
  const int q0 = blockIdx.x * 64 + wave * 16;
  const size_t bh = (size_t)b * 8 + h;
  const bf16* Qp = qkv + (bh << 16);
  const bf16* Kp = qkv + ((32 + bh) << 16);
  const bf16* Vg = qkv + ((64 + bh) << 16);     // [64 d][1024 n]

  // Q B-fragment (pre-scaled by 0.125 at QKV epilogue)
  bf16x8 qa0 = *(const bf16x8*)(Qp + (size_t)(q0 + c) * 64 + g * 8);
  bf16x8 qa1 = *(const bf16x8*)(Qp + (size_t)(q0 + c) * 64 + 32 + g * 8);

  const float pbq = pbw[bh * 1024 + q0 + c];
  const float cbq = cbw[bh * 1024 + q0 + c];
  const uint32_t* mrp = mpk + (((size_t)b * 1024 + q0 + c) << 10);

  f32x4 oacc[4] = {{0,0,0,0},{0,0,0,0},{0,0,0,0},{0,0,0,0}};
  float m = -1e30f, l = 0.f;

  for (int kt = 0; kt < 16; ++kt) {
    const int k0 = kt * 64;
    __syncthreads();                 // all waves done reading prev Kt/Vt
    // ---- async K DMA: slot (r,p) <- global chunk p^(r&7)   (512 chunks)
#pragma unroll
    for (int i = 0; i < 2; ++i) {
      int ib = i * 256 + wave * 64;
      int idx = ib + lane;
      int r = idx >> 3, p = idx & 7;
      gload16(Kp + (size_t)(k0 + r) * 64 + ((p ^ (r & 7)) * 8), Kt + ib * 8);
    }
    // ---- async V^T DMA: slot (d,p) <- global chunk p^(d&7)  (512 chunks)
#pragma unroll
    for (int i = 0; i < 2; ++i) {
      int ib = i * 256 + wave * 64;
      int idx = ib + lane;
      int d = idx >> 3, p = idx & 7;
      gload16(Vg + (size_t)d * 1024 + k0 + ((p ^ (d & 7)) * 8), Vt + ib * 8);
    }
    // ---- mask prefetch overlaps the DMA (keys nt*16 + 4g + 0..3)
    uint4 mu[4];
#pragma unroll
    for (int nt = 0; nt < 4; ++nt)
      mu[nt] = *(const uint4*)(mrp + k0 + nt * 16 + 4 * g);
    __syncthreads();                 // drains vmcnt: K, V, mask ready
    // ---- S^T = K·Q^T : lane gets col q=c, rows key = nt*16 + 4g + r
    f32x4 sacc[4];
#pragma unroll
    for (int nt = 0; nt < 4; ++nt) {
      f32x4 z = {0.f,0.f,0.f,0.f};
      int r = nt * 16 + c;           // r & 7 == c & 7
      bf16x8 k0f = *(const bf16x8*)(Kt + r * 64 + (( g      ^ (c & 7)) * 8));
      bf16x8 k1f = *(const bf16x8*)(Kt + r * 64 + (((4 + g) ^ (c & 7)) * 8));
      z = __builtin_amdgcn_mfma_f32_16x16x32_bf16(k0f, qa0, z, 0, 0, 0);
      z = __builtin_amdgcn_mfma_f32_16x16x32_bf16(k1f, qa1, z, 0, 0, 0);
      sacc[nt] = z;
    }
    // ---- bias + mask + per-lane online softmax
    float mx = -1e30f;
#pragma unroll
    for (int nt = 0; nt < 4; ++nt) {
      uint32_t uu[4] = {mu[nt].x, mu[nt].y, mu[nt].z, mu[nt].w};
#pragma unroll
      for (int r = 0; r < 4; ++r) {
        float s = sacc[nt][r] + bfhi(uu[r]) * pbq + bflo(uu[r]) * cbq;
        s = (uu[r] == 0xFFFFFFFFu) ? -1e30f : s;
        sacc[nt][r] = s;
        mx = fmaxf(mx, s);
      }
    }
    mx = fmaxf(mx, __shfl_xor(mx, 16));
    mx = fmaxf(mx, __shfl_xor(mx, 32));
    const float newm = fmaxf(m, mx);
    const float al = __expf(m - newm);
    float ps = 0.f;
#pragma unroll
    for (int nt = 0; nt < 4; ++nt) {
      float p0 = (sacc[nt][0] <= -1e29f) ? 0.f : __expf(sacc[nt][0] - newm);
      float p1 = (sacc[nt][1] <= -1e29f) ? 0.f : __expf(sacc[nt][1] - newm);
      float p2 = (sacc[nt][2] <= -1e29f) ? 0.f : __expf(sacc[nt][2] - newm);
      float p3 = (sacc[nt][3] <= -1e29f) ? 0.f : __expf(sacc[nt][3] - newm);
      ps += (p0 + p1) + (p2 + p3);
      uint2 w;
      w.x = (bfbits(p1) << 16) | bfbits(p0);
      w.y = (bfbits(p3) << 16) | bfbits(p2);
      *(uint2*)&Ps[wave][c][nt * 16 + 4 * g] = w;   // keys nt*16+4g..+3
    }
    ps += __shfl_xor(ps, 16);
    ps += __shfl_xor(ps, 32);
    l = l * al + ps;
    m = newm;
#pragma unroll
    for (int dt = 0; dt < 4; ++dt) {
      oacc[dt][0] *= al; oacc[dt][1] *= al;
      oacc[dt][2] *= al; oacc[dt][3] *= al;
    }
    // ---- PV: O^T[d][q] += sum_k V^T[d][k] * P[q][k]
#pragma unroll
    for (int dt = 0; dt < 4; ++dt) {
      int row = dt * 16 + c;         // row & 7 == c & 7
#pragma unroll
      for (int kc = 0; kc < 2; ++kc) {
        bf16x8 vf = *(const bf16x8*)(Vt + row * 64 + (((kc * 4 + g) ^ (c & 7)) * 8));
        bf16x8 pf = *(const bf16x8*)&Ps[wave][c][kc * 32 + g * 8];
        oacc[dt] = __builtin_amdgcn_mfma_f32_16x16x32_bf16(vf, pf, oacc[dt], 0, 0, 0);
      }
    }
  }
  const float inv = (l > 0.f) ? 1.f / l : 0.f;
  const int qg = q0 + c;
#pragma unroll
  for (int dt = 0; dt < 4; ++dt)
#pragma unroll
    for (int rg = 0; rg < 4; ++rg) {
      int d = dt * 16 + 4 * g + rg;
      ctxo[((size_t)qg * 4 + b) * 512 + h * 64 + d] =
          __float2bfloat16(oacc[dt][rg] * inv);
    }
}

// ---------------------------------------------------------------------------
// out = LayerNorm(a + p0 + p1 + bias) * g + be   (row = 512, wave per row)
// ---------------------------------------------------------------------------
template<typename TA, typename TO>
__global__ __launch_bounds__(256)
void ln_res2(const TA* __restrict__ a, const float* __restrict__ p0,
             const float* __restrict__ p1, const float* __restrict__ bias,
             const float* __restrict__ g, const float* __restrict__ be,
             TO* __restrict__ out)
{
  const int wave = threadIdx.x >> 6, lane = threadIdx.x & 63;
  const int m = blockIdx.x * 4 + wave;
  const size_t base = (size_t)m * 512 + lane * 8;
  float va[8], f0[8], f1[8], bb[8];
  load8(a + base, va);
  load8(p0 + base, f0);
  load8(p1 + base, f1);
  load8(bias + lane * 8, bb);
  float v[8], s = 0.f;
#pragma unroll
  for (int j = 0; j < 8; ++j) { v[j] = va[j] + f0[j] + f1[j] + bb[j]; s += v[j]; }
#pragma unroll
  for (int off = 32; off; off >>= 1) s += __shfl_xor(s, off);
  const float mean = s * (1.f / 512.f);
  float q = 0.f;
#pragma unroll
  for (int j = 0; j < 8; ++j) { float d = v[j] - mean; q += d * d; }
#pragma unroll
  for (int off = 32; off; off >>= 1) q += __shfl_xor(q, off);
  const float rs = rsqrtf(q * (1.f / 512.f) + 1e-5f);
  float gv[8], bv[8];
  load8(g + lane * 8, gv);
  load8(be + lane * 8, bv);
#pragma unroll
  for (int j = 0; j < 8; ++j)
    store1(out + base + j, (v[j] - mean) * rs * gv[j] + bv[j]);
}

// ---------------------------------------------------------------------------
extern "C" void kernel_launch(void* const* d_in, const int* in_sizes, int n_in,
                              void* d_out, int out_size, void* d_ws, size_t ws_size,
                              hipStream_t stream)
{
  (void)in_sizes; (void)n_in; (void)out_size; (void)ws_size;
  const float* x    = (const float*)d_in[0];
  const float* pm   = (const float*)d_in[1];
  const int*   hid  = (const int*)d_in[2];
  const int*   padm = (const int*)d_in[3];
  const float* Wp   = (const float*)d_in[4];
  const float* bp   = (const float*)d_in[5];
  const float* Wc   = (const float*)d_in[6];
  const float* bc   = (const float*)d_in[7];
  const float* Wqkv = (const float*)d_in[8];
  const float* bqkv = (const float*)d_in[9];
  const float* Wo   = (const float*)d_in[10];
  const float* bo   = (const float*)d_in[11];
  const float* W1   = (const float*)d_in[12];
  const float* b1   = (const float*)d_in[13];
  const float* W2   = (const float*)d_in[14];
  const float* b2   = (const float*)d_in[15];
  const float* g1   = (const float*)d_in[16];
  const float* be1  = (const float*)d_in[17];
  const float* g2   = (const float*)d_in[18];
  const float* be2  = (const float*)d_in[19];

  // Workspace (max 48,634,368 B; lifetimes: journal R7):
  char* ws = (char*)d_ws;
  bf16*     qkvb  = (bf16*)    (ws);               // 12.58 MB (QKV gemm -> attn)
  float*    pbo   = (float*)   (ws + 12582912);    // 128 KB  (qkv gemm -> attn)
  float*    cbo   = (float*)   (ws + 12713984);    // 128 KB  (= pbo + 32768 el)
  uint32_t* mpk   = (uint32_t*)(ws + 12845056);    // 16.78 MB (prologue -> attn)
  bf16*     ctx   = (bf16*)    (ws + 29622272);    // 4.19 MB (attn -> Wo gemm)
  float*    part  = (float*)   (ws);               // 16.78 MB split-K partials
                                                   //   (aliases qkvb/pbo/cbo/mpk-head;
                                                   //    dead after attn)
  bf16*     ff1   = (bf16*)    (ws + 16777216);    // 16.78 MB (aliases mpk tail + ctx;
                                                   //    dead when FF1 runs)
  bf16*     y     = (bf16*)    (ws + 33816576);    // 4.19 MB (ln1 -> ln2)
  bf16*     xb    = (bf16*)    (ws + 38010880);    // 4.19 MB
  bf16*     wqkvb = (bf16*)    (ws + 42205184);    // 1.70 MB (1664 x 512 bf16)
  bf16*     wob   = (bf16*)    (ws + 43909120);    // 512 KB
  bf16*     w1b   = (bf16*)    (ws + 44433408);    // 2.10 MB
  bf16*     w2b   = (bf16*)    (ws + 46530560);    // 2.10 MB
  float*    bext  = (float*)   (ws + 48627712);    // 6.5 KB (end 48,634,368)
  float*    part1 = part + (size_t)4096 * 512;

  prologue<<<3077, 256, 0, stream>>>(pm, hid, padm, mpk, x, Wqkv, Wo, W1, W2,
                                     xb, wqkvb, wob, w1b, w2b,
                                     bqkv, bp, bc, Wp, Wc, bext);
  gemm_bt<2, 128><<<dim3(13, 32), 256, 0, stream>>>(xb, wqkvb, bext, qkvb, pbo, 4096, 1664, 512, 512);
  attn_mfma<<<dim3(16, 8, 4), 256, 0, stream>>>(qkvb, pbo, cbo, mpk, ctx);
  gemm_bt<3, 64><<<dim3(8, 32, 2), 256, 0, stream>>>(ctx, wob, nullptr, nullptr, part, 4096, 512, 512, 256);
  ln_res2<float, bf16><<<1024, 256, 0, stream>>>(x, part, part1, bo, g1, be1, y);
  gemm_bt<1, 128><<<dim3(16, 32), 256, 0, stream>>>(y, w1b, b1, ff1, nullptr, 4096, 2048, 512, 512);
  gemm_bt<3, 64><<<dim3(8, 32, 2), 256, 0, stream>>>(ff1, w2b, nullptr, nullptr, part, 4096, 512, 2048, 1024);
  ln_res2<bf16, float><<<1024, 256, 0, stream>>>(y, part, part1, b2, g2, be2, (float*)d_out);
}

// Round 10
// 272.040 us; speedup vs baseline: 1.0934x; 1.0934x over previous
//
#include <hip/hip_runtime.h>
#include <hip/hip_bf16.h>
#include <stdint.h>

using bf16 = __hip_bfloat16;

typedef __bf16 bf16x8 __attribute__((ext_vector_type(8)));
typedef float  f32x4  __attribute__((ext_vector_type(4)));

__device__ __forceinline__ float bflo(uint32_t u) { return __uint_as_float(u << 16); }
__device__ __forceinline__ float bfhi(uint32_t u) { return __uint_as_float(u & 0xffff0000u); }

__device__ __forceinline__ void load8(const bf16* p, float* f) {
  uint4 u = *(const uint4*)p;
  f[0] = bflo(u.x); f[1] = bfhi(u.x);
  f[2] = bflo(u.y); f[3] = bfhi(u.y);
  f[4] = bflo(u.z); f[5] = bfhi(u.z);
  f[6] = bflo(u.w); f[7] = bfhi(u.w);
}
__device__ __forceinline__ void load8(const float* p, float* f) {
  float4 a = *(const float4*)p, b = *(const float4*)(p + 4);
  f[0] = a.x; f[1] = a.y; f[2] = a.z; f[3] = a.w;
  f[4] = b.x; f[5] = b.y; f[6] = b.z; f[7] = b.w;
}
__device__ __forceinline__ void store1(float* o, float v) { *o = v; }
__device__ __forceinline__ void store1(bf16* o, float v) { *o = __float2bfloat16(v); }
__device__ __forceinline__ uint32_t bfbits(float x) {
  bf16 v = __float2bfloat16(x);
  return (uint32_t)*(uint16_t*)&v;
}

// ---- async global->LDS, 16B per lane; lds base must be wave-uniform -------
typedef const uint32_t __attribute__((address_space(1)))* gp_t;
typedef uint32_t __attribute__((address_space(3)))* lp_t;
__device__ __forceinline__ void gload16(const void* g, void* l) {
  __builtin_amdgcn_global_load_lds((gp_t)g, (lp_t)l, 16, 0, 0);
}

// ---------------------------------------------------------------------------
// Fused prologue (one launch, block-range dispatch):
//  blocks 0..511     : mask_pack
//  blocks 512..3071  : cvt f32->bf16 of x,Wqkv,Wo,W1,W2
//  blocks 3072..3076 : prep_small (Wp/Wc rows + bias concat)
// ---------------------------------------------------------------------------
__global__ __launch_bounds__(256)
void prologue(const float* __restrict__ pm, const int* __restrict__ hid,
              const int* __restrict__ padm, uint32_t* __restrict__ mout,
              const float* __restrict__ x, const float* __restrict__ Wqkv,
              const float* __restrict__ Wo, const float* __restrict__ W1,
              const float* __restrict__ W2, bf16* __restrict__ xb,
              bf16* __restrict__ wq, bf16* __restrict__ wob,
              bf16* __restrict__ w1b, bf16* __restrict__ w2b,
              const float* __restrict__ bqkv, const float* __restrict__ bp,
              const float* __restrict__ bc, const float* __restrict__ Wp,
              const float* __restrict__ Wc, float* __restrict__ bias_ext)
{
  __shared__ float tileT[128][65];   // mask branch only
  const int blk = blockIdx.x, t = threadIdx.x;
  if (blk < 512) {
    const int k0 = (blk & 7) * 128, q0 = ((blk >> 3) & 15) * 64, b = blk >> 7;
    const size_t pb = (size_t)b << 20;
#pragma unroll
    for (int i = 0; i < 32; ++i) {
      int idx = t + i * 256;
      int r = idx >> 6, c = idx & 63;
      tileT[r][c] = pm[pb + (size_t)(k0 + r) * 1024 + q0 + c];
    }
    __syncthreads();
#pragma unroll
    for (int i = 0; i < 32; ++i) {
      int idx = t + i * 256;         // 64 q x 128 k
      int q = idx >> 7, k = idx & 127;
      size_t src = pb + (size_t)(q0 + q) * 1024 + k0 + k;
      int msk = hid[src] | padm[b * 1024 + k0 + k];
      uint32_t u = 0xFFFFFFFFu;
      if (!msk) u = (bfbits(tileT[k][q]) << 16) | bfbits(pm[src]);
      mout[src] = u;
    }
  } else if (blk < 3072) {
    size_t j = ((size_t)(blk - 512) * 256 + t) * 8;
    const float* s; bf16* o; size_t off;
    if      (j < 2097152) { s = x;    o = xb;  off = j; }
    else if (j < 2883584) { s = Wqkv; o = wq;  off = j - 2097152; }
    else if (j < 3145728) { s = Wo;   o = wob; off = j - 2883584; }
    else if (j < 4194304) { s = W1;   o = w1b; off = j - 3145728; }
    else                  { s = W2;   o = w2b; off = j - 4194304; }
    float f[8];
    load8(s + off, f);
    uint4 u;
    u.x = (bfbits(f[1]) << 16) | bfbits(f[0]);
    u.y = (bfbits(f[3]) << 16) | bfbits(f[2]);
    u.z = (bfbits(f[5]) << 16) | bfbits(f[4]);
    u.w = (bfbits(f[7]) << 16) | bfbits(f[6]);
    *(uint4*)(o + off) = u;
  } else {
    int sb = blk - 3072;
    if (sb < 2) {
      int j = (sb * 256 + t) * 8;
      if (j < 4096) {
        float f[8]; load8(Wp + j, f);
#pragma unroll
        for (int i = 0; i < 8; ++i) wq[(size_t)1536 * 512 + j + i] = __float2bfloat16(f[i]);
      }
    } else if (sb < 4) {
      int j = ((sb - 2) * 256 + t) * 8;
      if (j < 4096) {
        float f[8]; load8(Wc + j, f);
#pragma unroll
        for (int i = 0; i < 8; ++i) wq[(size_t)1544 * 512 + j + i] = __float2bfloat16(f[i]);
      }
    } else {
      int j = t * 8;
#pragma unroll
      for (int i = 0; i < 8; ++i) {
        int cc = j + i;
        if (cc < 1664) {
          float v = 0.f;
          if (cc < 1536) v = bqkv[cc];
          else if (cc < 1544) v = bp[cc - 1536];
          else if (cc < 1552) v = bc[cc - 1544];
          bias_ext[cc] = v;
        }
      }
    }
  }
}

// ---------------------------------------------------------------------------
// GEMM: C[M,Nout] = A[M,K(kOff..kOff+kLen)] * W^T + bias   (bf16, f32 accum)
// 128 x BN tile, global_load_lds(16B) staging, 4 waves.
// MODE 0: bf16 store. MODE 1: relu+bf16. MODE 3: f32 split-K partial.
// MODE 2: QKV+pb/cb: cols 0-511 Q (x0.125) -> [0][b][h][n][d]; 512-1023 K;
//         1024-1535 V transposed [b][h][d][n]; 1536-1551 pb/cb f32; >=1552 skip
// ---------------------------------------------------------------------------
template<int MODE, int BN>
__global__ __launch_bounds__(256)
void gemm_bt(const bf16* __restrict__ A, const bf16* __restrict__ W,
             const float* __restrict__ bias, bf16* __restrict__ outb,
             float* __restrict__ outf, int M, int Nout, int K, int kLen)
{
  constexpr int NT = BN / 32;
  __shared__ bf16 As[128 * 64];
  __shared__ bf16 Bs[BN * 64];
  const int t = threadIdx.x, lane = t & 63, wave = t >> 6;
  const int m0 = blockIdx.y * 128, n0 = blockIdx.x * BN;
  const int kOff = blockIdx.z * kLen;
  if (MODE == 3) outf += (size_t)blockIdx.z * M * Nout;
  const int wr = wave >> 1, wc = wave & 1;
  const int frow = lane & 15, ksel = (lane >> 4) * 8;
  f32x4 acc[4 * NT] = {};
  const bf16* Ab = A + (size_t)m0 * K;
  const bf16* Wb = W + (size_t)n0 * K;

  for (int k0 = kOff; k0 < kOff + kLen; k0 += 64) {
    __syncthreads();
#pragma unroll
    for (int i = 0; i < 4; ++i) {
      int ib = i * 256 + wave * 64;
      int idx = ib + lane;
      gload16(Ab + (size_t)(idx >> 3) * K + k0 + (idx & 7) * 8, As + ib * 8);
    }
#pragma unroll
    for (int i = 0; i < BN / 32; ++i) {
      int ib = i * 256 + wave * 64;
      int idx = ib + lane;
      gload16(Wb + (size_t)(idx >> 3) * K + k0 + (idx & 7) * 8, Bs + ib * 8);
    }
    __syncthreads();
#pragma unroll
    for (int kk = 0; kk < 64; kk += 32) {
      bf16x8 af[4], bf_[NT];
#pragma unroll
      for (int mt = 0; mt < 4; ++mt)
        af[mt] = *(const bf16x8*)(As + (wr * 64 + mt * 16 + frow) * 64 + kk + ksel);
#pragma unroll
      for (int nt = 0; nt < NT; ++nt)
        bf_[nt] = *(const bf16x8*)(Bs + (wc * (BN / 2) + nt * 16 + frow) * 64 + kk + ksel);
#pragma unroll
      for (int mt = 0; mt < 4; ++mt)
#pragma unroll
        for (int nt = 0; nt < NT; ++nt)
          acc[mt * NT + nt] = __builtin_amdgcn_mfma_f32_16x16x32_bf16(
              af[mt], bf_[nt], acc[mt * NT + nt], 0, 0, 0);
    }
  }
  const int rb = (lane >> 4) * 4, cb = lane & 15;
#pragma unroll
  for (int mt = 0; mt < 4; ++mt)
#pragma unroll
    for (int nt = 0; nt < NT; ++nt) {
      f32x4 a = acc[mt * NT + nt];
#pragma unroll
      for (int r = 0; r < 4; ++r) {
        int row = m0 + wr * 64 + mt * 16 + rb + r;
        int col = n0 + wc * (BN / 2) + nt * 16 + cb;
        if (MODE == 3) {
          outf[(size_t)row * Nout + col] = a[r];
        } else {
          float v = a[r] + bias[col];
          if (MODE == 1) v = fmaxf(v, 0.f);
          if (MODE == 2) {
            if (col >= 1552) continue;           // padding cols
            int n = row >> 2, b = row & 3;
            if (col >= 1536) {                   // pb/cb projections, f32
              int j = col - 1536;
              int hh = j & 7;
              outf[(j < 8 ? 0 : 32768) + (b * 8 + hh) * 1024 + n] = v;
            } else {
              int which = col >> 9, hh = (col >> 6) & 7, d = col & 63;
              if (which == 0) v *= 0.125f;       // fold 1/sqrt(HD) into Q
              size_t idx;
              if (which == 2)   // V transposed: [b][h][d][n]
                idx = (((size_t)(64 + b * 8 + hh)) << 16) + (size_t)d * 1024 + n;
              else              // Q,K: [which][b][h][n][d]
                idx = (((size_t)(which * 32 + b * 8 + hh)) << 16) + (size_t)n * 64 + d;
              outb[idx] = __float2bfloat16(v);
            }
          } else {
            outb[(size_t)row * Nout + col] = __float2bfloat16(v);
          }
        }
      }
    }
}

// ---------------------------------------------------------------------------
// MFMA flash attention, S^T form, split-KV x2. Block = 64 q of one (b,h) and
// HALF the key stream (512 keys, 4 tiles of 128). R8-proven tile structure:
// K/V DMA'd via global_load_lds with XOR chunk swizzle on the GLOBAL side.
// Writes un-normalized partial O (bf16) + per-row (m,l) for the merge.
// blockIdx.z: b = z>>1, half = z&1. Grid 16x8x8 = 1024 blocks.
// ---------------------------------------------------------------------------
__global__ __launch_bounds__(256, 3)
void attn_mfma(const bf16* __restrict__ qkv, const float* __restrict__ pbw,
               const float* __restrict__ cbw, const uint32_t* __restrict__ mpk,
               bf16* __restrict__ opart, float2* __restrict__ mlout)
{
  __shared__ bf16 Kt[128 * 64];    // [key][d] swizzled (DMA)
  __shared__ bf16 Vt[64 * 128];    // [d][key] swizzled (DMA)
  __shared__ bf16 Ps[4][16][136];  // per-wave P [q][key], stride 136 -> 2-way
  const int t = threadIdx.x, lane = t & 63, wave = t >> 6;
  const int g = lane >> 4, c = lane & 15;
  const int h = blockIdx.y, b = blockIdx.z >> 1, half = blockIdx.z & 1;
  const int q0 = blockIdx.x * 64 + wave * 16;
  const size_t bh = (size_t)b * 8 + h;
  const bf16* Qp = qkv + (bh << 16);
  const bf16* Kp = qkv + ((32 + bh) << 16);
  const bf16* Vg = qkv + ((64 + bh) << 16);     // [64 d][1024 n]

  // Q B-fragment (pre-scaled by 0.125 at QKV epilogue)
  bf16x8 qa0 = *(const bf16x8*)(Qp + (size_t)(q0 + c) * 64 + g * 8);
  bf16x8 qa1 = *(const bf16x8*)(Qp + (size_t)(q0 + c) * 64 + 32 + g * 8);

  const float pbq = pbw[bh * 1024 + q0 + c];
  const float cbq = cbw[bh * 1024 + q0 + c];
  const uint32_t* mrp = mpk + (((size_t)b * 1024 + q0 + c) << 10);

  f32x4 oacc[4] = {{0,0,0,0},{0,0,0,0},{0,0,0,0},{0,0,0,0}};
  float m = -1e30f, l = 0.f;

  for (int kt = 0; kt < 4; ++kt) {
    const int k0 = half * 512 + kt * 128;
    __syncthreads();                 // all waves done reading prev Kt/Vt
    // ---- async K DMA: slot (r,p) <- global chunk p^(r&7)
#pragma unroll
    for (int i = 0; i < 4; ++i) {
      int ib = i * 256 + wave * 64;
      int idx = ib + lane;
      int r = idx >> 3, p = idx & 7;
      gload16(Kp + (size_t)(k0 + r) * 64 + ((p ^ (r & 7)) * 8), Kt + ib * 8);
    }
    // ---- async V^T DMA: slot (d,p) <- global chunk p^(d&15)
#pragma unroll
    for (int i = 0; i < 4; ++i) {
      int ib = i * 256 + wave * 64;
      int idx = ib + lane;
      int d = idx >> 4, p = idx & 15;
      gload16(Vg + (size_t)d * 1024 + k0 + ((p ^ (d & 15)) * 8), Vt + ib * 8);
    }
    // ---- mask prefetch overlaps the DMA (keys nt*16 + 4g + 0..3)
    uint4 mu[8];
#pragma unroll
    for (int nt = 0; nt < 8; ++nt)
      mu[nt] = *(const uint4*)(mrp + k0 + nt * 16 + 4 * g);
    __syncthreads();                 // drains vmcnt: K, V, mask ready
    // ---- S^T = K·Q^T : lane gets col q=c, rows key = nt*16 + 4g + r
    f32x4 sacc[8];
#pragma unroll
    for (int nt = 0; nt < 8; ++nt) {
      f32x4 z = {0.f,0.f,0.f,0.f};
      int r = nt * 16 + c;           // r & 7 == c & 7
      bf16x8 k0f = *(const bf16x8*)(Kt + r * 64 + (( g      ^ (c & 7)) * 8));
      bf16x8 k1f = *(const bf16x8*)(Kt + r * 64 + (((4 + g) ^ (c & 7)) * 8));
      z = __builtin_amdgcn_mfma_f32_16x16x32_bf16(k0f, qa0, z, 0, 0, 0);
      z = __builtin_amdgcn_mfma_f32_16x16x32_bf16(k1f, qa1, z, 0, 0, 0);
      sacc[nt] = z;
    }
    // ---- bias + mask + per-lane online softmax
    float mx = -1e30f;
#pragma unroll
    for (int nt = 0; nt < 8; ++nt) {
      uint32_t uu[4] = {mu[nt].x, mu[nt].y, mu[nt].z, mu[nt].w};
#pragma unroll
      for (int r = 0; r < 4; ++r) {
        float s = sacc[nt][r] + bfhi(uu[r]) * pbq + bflo(uu[r]) * cbq;
        s = (uu[r] == 0xFFFFFFFFu) ? -1e30f : s;
        sacc[nt][r] = s;
        mx = fmaxf(mx, s);
      }
    }
    mx = fmaxf(mx, __shfl_xor(mx, 16));
    mx = fmaxf(mx, __shfl_xor(mx, 32));
    const float newm = fmaxf(m, mx);
    const float al = __expf(m - newm);
    float ps = 0.f;
#pragma unroll
    for (int nt = 0; nt < 8; ++nt) {
      float p0 = (sacc[nt][0] <= -1e29f) ? 0.f : __expf(sacc[nt][0] - newm);
      float p1 = (sacc[nt][1] <= -1e29f) ? 0.f : __expf(sacc[nt][1] - newm);
      float p2 = (sacc[nt][2] <= -1e29f) ? 0.f : __expf(sacc[nt][2] - newm);
      float p3 = (sacc[nt][3] <= -1e29f) ? 0.f : __expf(sacc[nt][3] - newm);
      ps += (p0 + p1) + (p2 + p3);
      uint2 w;
      w.x = (bfbits(p1) << 16) | bfbits(p0);
      w.y = (bfbits(p3) << 16) | bfbits(p2);
      *(uint2*)&Ps[wave][c][nt * 16 + 4 * g] = w;   // keys nt*16+4g..+3
    }
    ps += __shfl_xor(ps, 16);
    ps += __shfl_xor(ps, 32);
    l = l * al + ps;
    m = newm;
#pragma unroll
    for (int dt = 0; dt < 4; ++dt) {
      oacc[dt][0] *= al; oacc[dt][1] *= al;
      oacc[dt][2] *= al; oacc[dt][3] *= al;
    }
    // ---- PV: O^T[d][q] += sum_k V^T[d][k] * P[q][k]
#pragma unroll
    for (int dt = 0; dt < 4; ++dt) {
      int row = dt * 16 + c;         // row & 15 == c
#pragma unroll
      for (int kc = 0; kc < 4; ++kc) {
        bf16x8 vf = *(const bf16x8*)(Vt + row * 128 + (((kc * 4 + g) ^ c) * 8));
        bf16x8 pf = *(const bf16x8*)&Ps[wave][c][kc * 32 + g * 8];
        oacc[dt] = __builtin_amdgcn_mfma_f32_16x16x32_bf16(vf, pf, oacc[dt], 0, 0, 0);
      }
    }
  }
  // ---- write un-normalized partial + (m,l).  row = (half*32+bh)*1024 + q
  const int qg = q0 + c;
  const size_t prow = ((size_t)(half * 32) + bh) * 1024 + qg;
#pragma unroll
  for (int dt = 0; dt < 4; ++dt)
#pragma unroll
    for (int rg = 0; rg < 4; ++rg)
      opart[prow * 64 + dt * 16 + 4 * g + rg] = __float2bfloat16(oacc[dt][rg]);
  if (g == 0) mlout[prow] = make_float2(m, l);
}

// ---------------------------------------------------------------------------
// attn_reduce: merge the two KV halves. 262144 threads, 8 d-elems each.
// ---------------------------------------------------------------------------
__global__ __launch_bounds__(256)
void attn_reduce(const bf16* __restrict__ opart, const float2* __restrict__ ml,
                 bf16* __restrict__ ctxo)
{
  const int idx = blockIdx.x * 256 + threadIdx.x;
  const int row = idx >> 3, seg = (idx & 7) * 8;   // row in [0, 32768)
  float o0[8], o1[8];
  load8(opart + (size_t)row * 64 + seg, o0);
  load8(opart + (size_t)(row + 32768) * 64 + seg, o1);
  const float2 ml0 = ml[row], ml1 = ml[row + 32768];
  const float mst = fmaxf(ml0.x, ml1.x);
  const float w0 = __expf(ml0.x - mst), w1 = __expf(ml1.x - mst);
  const float denom = ml0.y * w0 + ml1.y * w1;
  const float inv = (denom > 0.f) ? 1.f / denom : 0.f;
  const int bh = row >> 10, q = row & 1023;
  const int b = bh >> 3, h = bh & 7;
  bf16* out = ctxo + ((size_t)q * 4 + b) * 512 + h * 64 + seg;
#pragma unroll
  for (int j = 0; j < 8; ++j)
    out[j] = __float2bfloat16((o0[j] * w0 + o1[j] * w1) * inv);
}

// ---------------------------------------------------------------------------
// out = LayerNorm(a + p0 + p1 + bias) * g + be   (row = 512, wave per row)
// ---------------------------------------------------------------------------
template<typename TA, typename TO>
__global__ __launch_bounds__(256)
void ln_res2(const TA* __restrict__ a, const float* __restrict__ p0,
             const float* __restrict__ p1, const float* __restrict__ bias,
             const float* __restrict__ g, const float* __restrict__ be,
             TO* __restrict__ out)
{
  const int wave = threadIdx.x >> 6, lane = threadIdx.x & 63;
  const int m = blockIdx.x * 4 + wave;
  const size_t base = (size_t)m * 512 + lane * 8;
  float va[8], f0[8], f1[8], bb[8];
  load8(a + base, va);
  load8(p0 + base, f0);
  load8(p1 + base, f1);
  load8(bias + lane * 8, bb);
  float v[8], s = 0.f;
#pragma unroll
  for (int j = 0; j < 8; ++j) { v[j] = va[j] + f0[j] + f1[j] + bb[j]; s += v[j]; }
#pragma unroll
  for (int off = 32; off; off >>= 1) s += __shfl_xor(s, off);
  const float mean = s * (1.f / 512.f);
  float q = 0.f;
#pragma unroll
  for (int j = 0; j < 8; ++j) { float d = v[j] - mean; q += d * d; }
#pragma unroll
  for (int off = 32; off; off >>= 1) q += __shfl_xor(q, off);
  const float rs = rsqrtf(q * (1.f / 512.f) + 1e-5f);
  float gv[8], bv[8];
  load8(g + lane * 8, gv);
  load8(be + lane * 8, bv);
#pragma unroll
  for (int j = 0; j < 8; ++j)
    store1(out + base + j, (v[j] - mean) * rs * gv[j] + bv[j]);
}

// ---------------------------------------------------------------------------
extern "C" void kernel_launch(void* const* d_in, const int* in_sizes, int n_in,
                              void* d_out, int out_size, void* d_ws, size_t ws_size,
                              hipStream_t stream)
{
  (void)in_sizes; (void)n_in; (void)out_size; (void)ws_size;
  const float* x    = (const float*)d_in[0];
  const float* pm   = (const float*)d_in[1];
  const int*   hid  = (const int*)d_in[2];
  const int*   padm = (const int*)d_in[3];
  const float* Wp   = (const float*)d_in[4];
  const float* bp   = (const float*)d_in[5];
  const float* Wc   = (const float*)d_in[6];
  const float* bc   = (const float*)d_in[7];
  const float* Wqkv = (const float*)d_in[8];
  const float* bqkv = (const float*)d_in[9];
  const float* Wo   = (const float*)d_in[10];
  const float* bo   = (const float*)d_in[11];
  const float* W1   = (const float*)d_in[12];
  const float* b1   = (const float*)d_in[13];
  const float* W2   = (const float*)d_in[14];
  const float* b2   = (const float*)d_in[15];
  const float* g1   = (const float*)d_in[16];
  const float* be1  = (const float*)d_in[17];
  const float* g2   = (const float*)d_in[18];
  const float* be2  = (const float*)d_in[19];

  // Workspace (max 57,547,264 B; lifetimes in journal):
  char* ws = (char*)d_ws;
  bf16*     qkvb  = (bf16*)    (ws);               // 12.58 MB (QKV gemm -> attn)
  float*    pbo   = (float*)   (ws + 12582912);    // 128 KB  (qkv gemm -> attn)
  float*    cbo   = (float*)   (ws + 12713984);    // 128 KB  (= pbo + 32768 el)
  uint32_t* mpk   = (uint32_t*)(ws + 12845056);    // 16.78 MB (prologue -> attn)
  bf16*     ctx   = (bf16*)    (ws + 29622272);    // 4.19 MB (reduce -> Wo gemm)
  float*    part  = (float*)   (ws);               // 16.78 MB split-K partials
                                                   //   (aliases qkvb/pbo/cbo/mpk-head;
                                                   //    dead after attn+reduce)
  bf16*     ff1   = (bf16*)    (ws + 16777216);    // 16.78 MB (aliases mpk tail + ctx;
                                                   //    dead when FF1 runs)
  bf16*     y     = (bf16*)    (ws + 33816576);    // 4.19 MB (ln1 -> ln2)
  bf16*     xb    = (bf16*)    (ws + 38010880);    // 4.19 MB
  bf16*     wqkvb = (bf16*)    (ws + 42205184);    // 1.70 MB (1664 x 512 bf16)
  bf16*     wob   = (bf16*)    (ws + 43909120);    // 512 KB
  bf16*     w1b   = (bf16*)    (ws + 44433408);    // 2.10 MB
  bf16*     w2b   = (bf16*)    (ws + 46530560);    // 2.10 MB
  float*    bext  = (float*)   (ws + 48627712);    // 6.5 KB
  bf16*     opart = (bf16*)    (ws + 48634368);    // 8.39 MB [2][32][1024][64]
  float2*   mlb   = (float2*)  (ws + 57022976);    // 512 KB  [2][32][1024]
                                                   // end 57,547,264
  float*    part1 = part + (size_t)4096 * 512;

  prologue<<<3077, 256, 0, stream>>>(pm, hid, padm, mpk, x, Wqkv, Wo, W1, W2,
                                     xb, wqkvb, wob, w1b, w2b,
                                     bqkv, bp, bc, Wp, Wc, bext);
  gemm_bt<2, 128><<<dim3(13, 32), 256, 0, stream>>>(xb, wqkvb, bext, qkvb, pbo, 4096, 1664, 512, 512);
  attn_mfma<<<dim3(16, 8, 8), 256, 0, stream>>>(qkvb, pbo, cbo, mpk, opart, mlb);
  attn_reduce<<<1024, 256, 0, stream>>>(opart, mlb, ctx);
  gemm_bt<3, 64><<<dim3(8, 32, 2), 256, 0, stream>>>(ctx, wob, nullptr, nullptr, part, 4096, 512, 512, 256);
  ln_res2<float, bf16><<<1024, 256, 0, stream>>>(x, part, part1, bo, g1, be1, y);
  gemm_bt<1, 128><<<dim3(16, 32), 256, 0, stream>>>(y, w1b, b1, ff1, nullptr, 4096, 2048, 512, 512);
  gemm_bt<3, 64><<<dim3(8, 32, 2), 256, 0, stream>>>(ff1, w2b, nullptr, nullptr, part, 4096, 512, 2048, 1024);
  ln_res2<bf16, float><<<1024, 256, 0, stream>>>(y, part, part1, b2, g2, be2, (float*)d_out);
}

// Round 11
// 271.002 us; speedup vs baseline: 1.0975x; 1.0038x over previous
//
#include <hip/hip_runtime.h>
#include <hip/hip_bf16.h>
#include <stdint.h>

using bf16 = __hip_bfloat16;

typedef __bf16 bf16x8 __attribute__((ext_vector_type(8)));
typedef float  f32x4  __attribute__((ext_vector_type(4)));

__device__ __forceinline__ float bflo(uint32_t u) { return __uint_as_float(u << 16); }
__device__ __forceinline__ float bfhi(uint32_t u) { return __uint_as_float(u & 0xffff0000u); }

__device__ __forceinline__ void load8(const bf16* p, float* f) {
  uint4 u = *(const uint4*)p;
  f[0] = bflo(u.x); f[1] = bfhi(u.x);
  f[2] = bflo(u.y); f[3] = bfhi(u.y);
  f[4] = bflo(u.z); f[5] = bfhi(u.z);
  f[6] = bflo(u.w); f[7] = bfhi(u.w);
}
__device__ __forceinline__ void load8(const float* p, float* f) {
  float4 a = *(const float4*)p, b = *(const float4*)(p + 4);
  f[0] = a.x; f[1] = a.y; f[2] = a.z; f[3] = a.w;
  f[4] = b.x; f[5] = b.y; f[6] = b.z; f[7] = b.w;
}
__device__ __forceinline__ void store1(float* o, float v) { *o = v; }
__device__ __forceinline__ void store1(bf16* o, float v) { *o = __float2bfloat16(v); }
__device__ __forceinline__ uint32_t bfbits(float x) {
  bf16 v = __float2bfloat16(x);
  return (uint32_t)*(uint16_t*)&v;
}

// ---- async global->LDS, 16B per lane; lds base must be wave-uniform -------
typedef const uint32_t __attribute__((address_space(1)))* gp_t;
typedef uint32_t __attribute__((address_space(3)))* lp_t;
__device__ __forceinline__ void gload16(const void* g, void* l) {
  __builtin_amdgcn_global_load_lds((gp_t)g, (lp_t)l, 16, 0, 0);
}

// ---------------------------------------------------------------------------
// cvt_prep: ZERO-LDS streaming kernel (full occupancy).
//  blocks 0..2559  : f32->bf16 of x,Wqkv,Wo,W1,W2
//  blocks 2560..64 : Wp/Wc rows into wq rows 1536..1551 + bias concat
// ---------------------------------------------------------------------------
__global__ __launch_bounds__(256)
void cvt_prep(const float* __restrict__ x, const float* __restrict__ Wqkv,
              const float* __restrict__ Wo, const float* __restrict__ W1,
              const float* __restrict__ W2, bf16* __restrict__ xb,
              bf16* __restrict__ wq, bf16* __restrict__ wob,
              bf16* __restrict__ w1b, bf16* __restrict__ w2b,
              const float* __restrict__ bqkv, const float* __restrict__ bp,
              const float* __restrict__ bc, const float* __restrict__ Wp,
              const float* __restrict__ Wc, float* __restrict__ bias_ext)
{
  const int blk = blockIdx.x, t = threadIdx.x;
  if (blk < 2560) {
    size_t j = ((size_t)blk * 256 + t) * 8;
    const float* s; bf16* o; size_t off;
    if      (j < 2097152) { s = x;    o = xb;  off = j; }
    else if (j < 2883584) { s = Wqkv; o = wq;  off = j - 2097152; }
    else if (j < 3145728) { s = Wo;   o = wob; off = j - 2883584; }
    else if (j < 4194304) { s = W1;   o = w1b; off = j - 3145728; }
    else                  { s = W2;   o = w2b; off = j - 4194304; }
    float f[8];
    load8(s + off, f);
    uint4 u;
    u.x = (bfbits(f[1]) << 16) | bfbits(f[0]);
    u.y = (bfbits(f[3]) << 16) | bfbits(f[2]);
    u.z = (bfbits(f[5]) << 16) | bfbits(f[4]);
    u.w = (bfbits(f[7]) << 16) | bfbits(f[6]);
    *(uint4*)(o + off) = u;
  } else {
    int sb = blk - 2560;
    if (sb < 2) {
      int j = (sb * 256 + t) * 8;
      if (j < 4096) {
        float f[8]; load8(Wp + j, f);
#pragma unroll
        for (int i = 0; i < 8; ++i) wq[(size_t)1536 * 512 + j + i] = __float2bfloat16(f[i]);
      }
    } else if (sb < 4) {
      int j = ((sb - 2) * 256 + t) * 8;
      if (j < 4096) {
        float f[8]; load8(Wc + j, f);
#pragma unroll
        for (int i = 0; i < 8; ++i) wq[(size_t)1544 * 512 + j + i] = __float2bfloat16(f[i]);
      }
    } else {
      int j = t * 8;
#pragma unroll
      for (int i = 0; i < 8; ++i) {
        int cc = j + i;
        if (cc < 1664) {
          float v = 0.f;
          if (cc < 1536) v = bqkv[cc];
          else if (cc < 1544) v = bp[cc - 1536];
          else if (cc < 1552) v = bc[cc - 1544];
          bias_ext[cc] = v;
        }
      }
    }
  }
}

// ---------------------------------------------------------------------------
// qkv_mask: fused QKV-projection GEMM + mask_pack in ONE launch.
//  blocks 0..415   : 128x128 MFMA gemm C = xb * wq^T + bias (QKV+pb/cb scatter)
//  blocks 416..927 : mask_pack (pm transpose + hid/pad -> packed uint32)
// LDS is a 33.3 KB union -> 4 blocks/CU; gemm is grid-limited anyway, mask
// blocks fill CUs left idle by the gemm's latency stalls.
// ---------------------------------------------------------------------------
__global__ __launch_bounds__(256)
void qkv_mask(const bf16* __restrict__ A, const bf16* __restrict__ W,
              const float* __restrict__ bias, bf16* __restrict__ outb,
              float* __restrict__ outf,
              const float* __restrict__ pm, const int* __restrict__ hid,
              const int* __restrict__ padm, uint32_t* __restrict__ mout)
{
  __shared__ char smem[33280];
  const int blk = blockIdx.x, t = threadIdx.x;
  if (blk < 416) {
    // ---- QKV GEMM: M=4096, Nout=1664, K=512 (one K-slice)
    bf16* As = (bf16*)smem;            // 128*64*2 = 16384
    bf16* Bs = (bf16*)(smem + 16384);  // 128*64*2 = 16384
    const int lane = t & 63, wave = t >> 6;
    const int m0 = (blk / 13) * 128, n0 = (blk % 13) * 128;
    const int wr = wave >> 1, wc = wave & 1;
    const int frow = lane & 15, ksel = (lane >> 4) * 8;
    f32x4 acc[16] = {};
    const bf16* Ab = A + (size_t)m0 * 512;
    const bf16* Wb = W + (size_t)n0 * 512;
    for (int k0 = 0; k0 < 512; k0 += 64) {
      __syncthreads();
#pragma unroll
      for (int i = 0; i < 4; ++i) {
        int ib = i * 256 + wave * 64;
        int idx = ib + lane;
        gload16(Ab + (size_t)(idx >> 3) * 512 + k0 + (idx & 7) * 8, As + ib * 8);
      }
#pragma unroll
      for (int i = 0; i < 4; ++i) {
        int ib = i * 256 + wave * 64;
        int idx = ib + lane;
        gload16(Wb + (size_t)(idx >> 3) * 512 + k0 + (idx & 7) * 8, Bs + ib * 8);
      }
      __syncthreads();
#pragma unroll
      for (int kk = 0; kk < 64; kk += 32) {
        bf16x8 af[4], bf_[4];
#pragma unroll
        for (int mt = 0; mt < 4; ++mt)
          af[mt] = *(const bf16x8*)(As + (wr * 64 + mt * 16 + frow) * 64 + kk + ksel);
#pragma unroll
        for (int nt = 0; nt < 4; ++nt)
          bf_[nt] = *(const bf16x8*)(Bs + (wc * 64 + nt * 16 + frow) * 64 + kk + ksel);
#pragma unroll
        for (int mt = 0; mt < 4; ++mt)
#pragma unroll
          for (int nt = 0; nt < 4; ++nt)
            acc[mt * 4 + nt] = __builtin_amdgcn_mfma_f32_16x16x32_bf16(
                af[mt], bf_[nt], acc[mt * 4 + nt], 0, 0, 0);
      }
    }
    const int rb = (lane >> 4) * 4, cb = lane & 15;
#pragma unroll
    for (int mt = 0; mt < 4; ++mt)
#pragma unroll
      for (int nt = 0; nt < 4; ++nt) {
        f32x4 a = acc[mt * 4 + nt];
#pragma unroll
        for (int r = 0; r < 4; ++r) {
          int row = m0 + wr * 64 + mt * 16 + rb + r;
          int col = n0 + wc * 64 + nt * 16 + cb;
          if (col >= 1552) continue;             // padding cols
          float v = a[r] + bias[col];
          int n = row >> 2, b = row & 3;
          if (col >= 1536) {                     // pb/cb projections, f32
            int j = col - 1536;
            int hh = j & 7;
            outf[(j < 8 ? 0 : 32768) + (b * 8 + hh) * 1024 + n] = v;
          } else {
            int which = col >> 9, hh = (col >> 6) & 7, d = col & 63;
            if (which == 0) v *= 0.125f;         // fold 1/sqrt(HD) into Q
            size_t idx;
            if (which == 2)   // V transposed: [b][h][d][n]
              idx = (((size_t)(64 + b * 8 + hh)) << 16) + (size_t)d * 1024 + n;
            else              // Q,K: [which][b][h][n][d]
              idx = (((size_t)(which * 32 + b * 8 + hh)) << 16) + (size_t)n * 64 + d;
            outb[idx] = __float2bfloat16(v);
          }
        }
      }
  } else {
    // ---- mask_pack
    float (*tileT)[65] = (float(*)[65])smem;     // 128*65*4 = 33280
    const int mb = blk - 416;
    const int k0 = (mb & 7) * 128, q0 = ((mb >> 3) & 15) * 64, b = mb >> 7;
    const size_t pb = (size_t)b << 20;
#pragma unroll
    for (int i = 0; i < 32; ++i) {
      int idx = t + i * 256;
      int r = idx >> 6, c = idx & 63;
      tileT[r][c] = pm[pb + (size_t)(k0 + r) * 1024 + q0 + c];
    }
    __syncthreads();
#pragma unroll
    for (int i = 0; i < 32; ++i) {
      int idx = t + i * 256;         // 64 q x 128 k
      int q = idx >> 7, k = idx & 127;
      size_t src = pb + (size_t)(q0 + q) * 1024 + k0 + k;
      int msk = hid[src] | padm[b * 1024 + k0 + k];
      uint32_t u = 0xFFFFFFFFu;
      if (!msk) u = (bfbits(tileT[k][q]) << 16) | bfbits(pm[src]);
      mout[src] = u;
    }
  }
}

// ---------------------------------------------------------------------------
// GEMM: C[M,Nout] = A[M,K(kOff..kOff+kLen)] * W^T + bias   (bf16, f32 accum)
// 128 x BN tile, global_load_lds(16B) staging, 4 waves.
// MODE 0: bf16 store. MODE 1: relu+bf16. MODE 3: f32 split-K partial.
// ---------------------------------------------------------------------------
template<int MODE, int BN>
__global__ __launch_bounds__(256)
void gemm_bt(const bf16* __restrict__ A, const bf16* __restrict__ W,
             const float* __restrict__ bias, bf16* __restrict__ outb,
             float* __restrict__ outf, int M, int Nout, int K, int kLen)
{
  constexpr int NT = BN / 32;
  __shared__ bf16 As[128 * 64];
  __shared__ bf16 Bs[BN * 64];
  const int t = threadIdx.x, lane = t & 63, wave = t >> 6;
  const int m0 = blockIdx.y * 128, n0 = blockIdx.x * BN;
  const int kOff = blockIdx.z * kLen;
  if (MODE == 3) outf += (size_t)blockIdx.z * M * Nout;
  const int wr = wave >> 1, wc = wave & 1;
  const int frow = lane & 15, ksel = (lane >> 4) * 8;
  f32x4 acc[4 * NT] = {};
  const bf16* Ab = A + (size_t)m0 * K;
  const bf16* Wb = W + (size_t)n0 * K;

  for (int k0 = kOff; k0 < kOff + kLen; k0 += 64) {
    __syncthreads();
#pragma unroll
    for (int i = 0; i < 4; ++i) {
      int ib = i * 256 + wave * 64;
      int idx = ib + lane;
      gload16(Ab + (size_t)(idx >> 3) * K + k0 + (idx & 7) * 8, As + ib * 8);
    }
#pragma unroll
    for (int i = 0; i < BN / 32; ++i) {
      int ib = i * 256 + wave * 64;
      int idx = ib + lane;
      gload16(Wb + (size_t)(idx >> 3) * K + k0 + (idx & 7) * 8, Bs + ib * 8);
    }
    __syncthreads();
#pragma unroll
    for (int kk = 0; kk < 64; kk += 32) {
      bf16x8 af[4], bf_[NT];
#pragma unroll
      for (int mt = 0; mt < 4; ++mt)
        af[mt] = *(const bf16x8*)(As + (wr * 64 + mt * 16 + frow) * 64 + kk + ksel);
#pragma unroll
      for (int nt = 0; nt < NT; ++nt)
        bf_[nt] = *(const bf16x8*)(Bs + (wc * (BN / 2) + nt * 16 + frow) * 64 + kk + ksel);
#pragma unroll
      for (int mt = 0; mt < 4; ++mt)
#pragma unroll
        for (int nt = 0; nt < NT; ++nt)
          acc[mt * NT + nt] = __builtin_amdgcn_mfma_f32_16x16x32_bf16(
              af[mt], bf_[nt], acc[mt * NT + nt], 0, 0, 0);
    }
  }
  const int rb = (lane >> 4) * 4, cb = lane & 15;
#pragma unroll
  for (int mt = 0; mt < 4; ++mt)
#pragma unroll
    for (int nt = 0; nt < NT; ++nt) {
      f32x4 a = acc[mt * NT + nt];
#pragma unroll
      for (int r = 0; r < 4; ++r) {
        int row = m0 + wr * 64 + mt * 16 + rb + r;
        int col = n0 + wc * (BN / 2) + nt * 16 + cb;
        if (MODE == 3) {
          outf[(size_t)row * Nout + col] = a[r];
        } else {
          float v = a[r] + bias[col];
          if (MODE == 1) v = fmaxf(v, 0.f);
          outb[(size_t)row * Nout + col] = __float2bfloat16(v);
        }
      }
    }
}

// ---------------------------------------------------------------------------
// MFMA flash attention, S^T form, split-KV x2 (R10 structure, R8 tile).
// ---------------------------------------------------------------------------
__global__ __launch_bounds__(256, 3)
void attn_mfma(const bf16* __restrict__ qkv, const float* __restrict__ pbw,
               const float* __restrict__ cbw, const uint32_t* __restrict__ mpk,
               bf16* __restrict__ opart, float2* __restrict__ mlout)
{
  __shared__ bf16 Kt[128 * 64];    // [key][d] swizzled (DMA)
  __shared__ bf16 Vt[64 * 128];    // [d][key] swizzled (DMA)
  __shared__ bf16 Ps[4][16][136];  // per-wave P [q][key], stride 136 -> 2-way
  const int t = threadIdx.x, lane = t & 63, wave = t >> 6;
  const int g = lane >> 4, c = lane & 15;
  const int h = blockIdx.y, b = blockIdx.z >> 1, half = blockIdx.z & 1;
  const int q0 = blockIdx.x * 64 + wave * 16;
  const size_t bh = (size_t)b * 8 + h;
  const bf16* Qp = qkv + (bh << 16);
  const bf16* Kp = qkv + ((32 + bh) << 16);
  const bf16* Vg = qkv + ((64 + bh) << 16);     // [64 d][1024 n]

  bf16x8 qa0 = *(const bf16x8*)(Qp + (size_t)(q0 + c) * 64 + g * 8);
  bf16x8 qa1 = *(const bf16x8*)(Qp + (size_t)(q0 + c) * 64 + 32 + g * 8);

  const float pbq = pbw[bh * 1024 + q0 + c];
  const float cbq = cbw[bh * 1024 + q0 + c];
  const uint32_t* mrp = mpk + (((size_t)b * 1024 + q0 + c) << 10);

  f32x4 oacc[4] = {{0,0,0,0},{0,0,0,0},{0,0,0,0},{0,0,0,0}};
  float m = -1e30f, l = 0.f;

  for (int kt = 0; kt < 4; ++kt) {
    const int k0 = half * 512 + kt * 128;
    __syncthreads();
#pragma unroll
    for (int i = 0; i < 4; ++i) {    // K DMA: slot (r,p) <- chunk p^(r&7)
      int ib = i * 256 + wave * 64;
      int idx = ib + lane;
      int r = idx >> 3, p = idx & 7;
      gload16(Kp + (size_t)(k0 + r) * 64 + ((p ^ (r & 7)) * 8), Kt + ib * 8);
    }
#pragma unroll
    for (int i = 0; i < 4; ++i) {    // V DMA: slot (d,p) <- chunk p^(d&15)
      int ib = i * 256 + wave * 64;
      int idx = ib + lane;
      int d = idx >> 4, p = idx & 15;
      gload16(Vg + (size_t)d * 1024 + k0 + ((p ^ (d & 15)) * 8), Vt + ib * 8);
    }
    uint4 mu[8];
#pragma unroll
    for (int nt = 0; nt < 8; ++nt)
      mu[nt] = *(const uint4*)(mrp + k0 + nt * 16 + 4 * g);
    __syncthreads();
    f32x4 sacc[8];
#pragma unroll
    for (int nt = 0; nt < 8; ++nt) {
      f32x4 z = {0.f,0.f,0.f,0.f};
      int r = nt * 16 + c;           // r & 7 == c & 7
      bf16x8 k0f = *(const bf16x8*)(Kt + r * 64 + (( g      ^ (c & 7)) * 8));
      bf16x8 k1f = *(const bf16x8*)(Kt + r * 64 + (((4 + g) ^ (c & 7)) * 8));
      z = __builtin_amdgcn_mfma_f32_16x16x32_bf16(k0f, qa0, z, 0, 0, 0);
      z = __builtin_amdgcn_mfma_f32_16x16x32_bf16(k1f, qa1, z, 0, 0, 0);
      sacc[nt] = z;
    }
    float mx = -1e30f;
#pragma unroll
    for (int nt = 0; nt < 8; ++nt) {
      uint32_t uu[4] = {mu[nt].x, mu[nt].y, mu[nt].z, mu[nt].w};
#pragma unroll
      for (int r = 0; r < 4; ++r) {
        float s = sacc[nt][r] + bfhi(uu[r]) * pbq + bflo(uu[r]) * cbq;
        s = (uu[r] == 0xFFFFFFFFu) ? -1e30f : s;
        sacc[nt][r] = s;
        mx = fmaxf(mx, s);
      }
    }
    mx = fmaxf(mx, __shfl_xor(mx, 16));
    mx = fmaxf(mx, __shfl_xor(mx, 32));
    const float newm = fmaxf(m, mx);
    const float al = __expf(m - newm);
    float ps = 0.f;
#pragma unroll
    for (int nt = 0; nt < 8; ++nt) {
      float p0 = (sacc[nt][0] <= -1e29f) ? 0.f : __expf(sacc[nt][0] - newm);
      float p1 = (sacc[nt][1] <= -1e29f) ? 0.f : __expf(sacc[nt][1] - newm);
      float p2 = (sacc[nt][2] <= -1e29f) ? 0.f : __expf(sacc[nt][2] - newm);
      float p3 = (sacc[nt][3] <= -1e29f) ? 0.f : __expf(sacc[nt][3] - newm);
      ps += (p0 + p1) + (p2 + p3);
      uint2 w;
      w.x = (bfbits(p1) << 16) | bfbits(p0);
      w.y = (bfbits(p3) << 16) | bfbits(p2);
      *(uint2*)&Ps[wave][c][nt * 16 + 4 * g] = w;
    }
    ps += __shfl_xor(ps, 16);
    ps += __shfl_xor(ps, 32);
    l = l * al + ps;
    m = newm;
#pragma unroll
    for (int dt = 0; dt < 4; ++dt) {
      oacc[dt][0] *= al; oacc[dt][1] *= al;
      oacc[dt][2] *= al; oacc[dt][3] *= al;
    }
#pragma unroll
    for (int dt = 0; dt < 4; ++dt) {
      int row = dt * 16 + c;         // row & 15 == c
#pragma unroll
      for (int kc = 0; kc < 4; ++kc) {
        bf16x8 vf = *(const bf16x8*)(Vt + row * 128 + (((kc * 4 + g) ^ c) * 8));
        bf16x8 pf = *(const bf16x8*)&Ps[wave][c][kc * 32 + g * 8];
        oacc[dt] = __builtin_amdgcn_mfma_f32_16x16x32_bf16(vf, pf, oacc[dt], 0, 0, 0);
      }
    }
  }
  const int qg = q0 + c;
  const size_t prow = ((size_t)(half * 32) + bh) * 1024 + qg;
#pragma unroll
  for (int dt = 0; dt < 4; ++dt)
#pragma unroll
    for (int rg = 0; rg < 4; ++rg)
      opart[prow * 64 + dt * 16 + 4 * g + rg] = __float2bfloat16(oacc[dt][rg]);
  if (g == 0) mlout[prow] = make_float2(m, l);
}

// ---------------------------------------------------------------------------
// attn_reduce: merge the two KV halves. 262144 threads, 8 d-elems each.
// ---------------------------------------------------------------------------
__global__ __launch_bounds__(256)
void attn_reduce(const bf16* __restrict__ opart, const float2* __restrict__ ml,
                 bf16* __restrict__ ctxo)
{
  const int idx = blockIdx.x * 256 + threadIdx.x;
  const int row = idx >> 3, seg = (idx & 7) * 8;   // row in [0, 32768)
  float o0[8], o1[8];
  load8(opart + (size_t)row * 64 + seg, o0);
  load8(opart + (size_t)(row + 32768) * 64 + seg, o1);
  const float2 ml0 = ml[row], ml1 = ml[row + 32768];
  const float mst = fmaxf(ml0.x, ml1.x);
  const float w0 = __expf(ml0.x - mst), w1 = __expf(ml1.x - mst);
  const float denom = ml0.y * w0 + ml1.y * w1;
  const float inv = (denom > 0.f) ? 1.f / denom : 0.f;
  const int bh = row >> 10, q = row & 1023;
  const int b = bh >> 3, h = bh & 7;
  bf16* out = ctxo + ((size_t)q * 4 + b) * 512 + h * 64 + seg;
#pragma unroll
  for (int j = 0; j < 8; ++j)
    out[j] = __float2bfloat16((o0[j] * w0 + o1[j] * w1) * inv);
}

// ---------------------------------------------------------------------------
// out = LayerNorm(a + p0 + p1 + bias) * g + be   (row = 512, wave per row)
// ---------------------------------------------------------------------------
template<typename TA, typename TO>
__global__ __launch_bounds__(256)
void ln_res2(const TA* __restrict__ a, const float* __restrict__ p0,
             const float* __restrict__ p1, const float* __restrict__ bias,
             const float* __restrict__ g, const float* __restrict__ be,
             TO* __restrict__ out)
{
  const int wave = threadIdx.x >> 6, lane = threadIdx.x & 63;
  const int m = blockIdx.x * 4 + wave;
  const size_t base = (size_t)m * 512 + lane * 8;
  float va[8], f0[8], f1[8], bb[8];
  load8(a + base, va);
  load8(p0 + base, f0);
  load8(p1 + base, f1);
  load8(bias + lane * 8, bb);
  float v[8], s = 0.f;
#pragma unroll
  for (int j = 0; j < 8; ++j) { v[j] = va[j] + f0[j] + f1[j] + bb[j]; s += v[j]; }
#pragma unroll
  for (int off = 32; off; off >>= 1) s += __shfl_xor(s, off);
  const float mean = s * (1.f / 512.f);
  float q = 0.f;
#pragma unroll
  for (int j = 0; j < 8; ++j) { float d = v[j] - mean; q += d * d; }
#pragma unroll
  for (int off = 32; off; off >>= 1) q += __shfl_xor(q, off);
  const float rs = rsqrtf(q * (1.f / 512.f) + 1e-5f);
  float gv[8], bv[8];
  load8(g + lane * 8, gv);
  load8(be + lane * 8, bv);
#pragma unroll
  for (int j = 0; j < 8; ++j)
    store1(out + base + j, (v[j] - mean) * rs * gv[j] + bv[j]);
}

// ---------------------------------------------------------------------------
extern "C" void kernel_launch(void* const* d_in, const int* in_sizes, int n_in,
                              void* d_out, int out_size, void* d_ws, size_t ws_size,
                              hipStream_t stream)
{
  (void)in_sizes; (void)n_in; (void)out_size; (void)ws_size;
  const float* x    = (const float*)d_in[0];
  const float* pm   = (const float*)d_in[1];
  const int*   hid  = (const int*)d_in[2];
  const int*   padm = (const int*)d_in[3];
  const float* Wp   = (const float*)d_in[4];
  const float* bp   = (const float*)d_in[5];
  const float* Wc   = (const float*)d_in[6];
  const float* bc   = (const float*)d_in[7];
  const float* Wqkv = (const float*)d_in[8];
  const float* bqkv = (const float*)d_in[9];
  const float* Wo   = (const float*)d_in[10];
  const float* bo   = (const float*)d_in[11];
  const float* W1   = (const float*)d_in[12];
  const float* b1   = (const float*)d_in[13];
  const float* W2   = (const float*)d_in[14];
  const float* b2   = (const float*)d_in[15];
  const float* g1   = (const float*)d_in[16];
  const float* be1  = (const float*)d_in[17];
  const float* g2   = (const float*)d_in[18];
  const float* be2  = (const float*)d_in[19];

  // Workspace (max 57,547,264 B; lifetimes in journal):
  char* ws = (char*)d_ws;
  bf16*     qkvb  = (bf16*)    (ws);               // 12.58 MB (qkv_mask -> attn)
  float*    pbo   = (float*)   (ws + 12582912);    // 128 KB
  float*    cbo   = (float*)   (ws + 12713984);    // 128 KB  (= pbo + 32768 el)
  uint32_t* mpk   = (uint32_t*)(ws + 12845056);    // 16.78 MB (qkv_mask -> attn)
  bf16*     ctx   = (bf16*)    (ws + 29622272);    // 4.19 MB (reduce -> Wo gemm)
  float*    part  = (float*)   (ws);               // 16.78 MB split-K partials
  bf16*     ff1   = (bf16*)    (ws + 16777216);    // 16.78 MB (aliases mpk tail + ctx)
  bf16*     y     = (bf16*)    (ws + 33816576);    // 4.19 MB (ln1 -> ln2)
  bf16*     xb    = (bf16*)    (ws + 38010880);    // 4.19 MB
  bf16*     wqkvb = (bf16*)    (ws + 42205184);    // 1.70 MB (1664 x 512 bf16)
  bf16*     wob   = (bf16*)    (ws + 43909120);    // 512 KB
  bf16*     w1b   = (bf16*)    (ws + 44433408);    // 2.10 MB
  bf16*     w2b   = (bf16*)    (ws + 46530560);    // 2.10 MB
  float*    bext  = (float*)   (ws + 48627712);    // 6.5 KB
  bf16*     opart = (bf16*)    (ws + 48634368);    // 8.39 MB [2][32][1024][64]
  float2*   mlb   = (float2*)  (ws + 57022976);    // 512 KB  [2][32][1024]
  float*    part1 = part + (size_t)4096 * 512;

  cvt_prep<<<2565, 256, 0, stream>>>(x, Wqkv, Wo, W1, W2, xb, wqkvb, wob, w1b, w2b,
                                     bqkv, bp, bc, Wp, Wc, bext);
  qkv_mask<<<928, 256, 0, stream>>>(xb, wqkvb, bext, qkvb, pbo,
                                    pm, hid, padm, mpk);
  attn_mfma<<<dim3(16, 8, 8), 256, 0, stream>>>(qkvb, pbo, cbo, mpk, opart, mlb);
  attn_reduce<<<1024, 256, 0, stream>>>(opart, mlb, ctx);
  gemm_bt<3, 64><<<dim3(8, 32, 2), 256, 0, stream>>>(ctx, wob, nullptr, nullptr, part, 4096, 512, 512, 256);
  ln_res2<float, bf16><<<1024, 256, 0, stream>>>(x, part, part1, bo, g1, be1, y);
  gemm_bt<1, 128><<<dim3(16, 32), 256, 0, stream>>>(y, w1b, b1, ff1, nullptr, 4096, 2048, 512, 512);
  gemm_bt<3, 64><<<dim3(8, 32, 2), 256, 0, stream>>>(ff1, w2b, nullptr, nullptr, part, 4096, 512, 2048, 1024);
  ln_res2<bf16, float><<<1024, 256, 0, stream>>>(y, part, part1, b2, g2, be2, (float*)d_out);
}